// Round 5
// baseline (104.760 us; speedup 1.0000x reference)
//
#include <hip/hip_runtime.h>
#include <hip/hip_bf16.h>

#define NPTS 2048
#define CH 32
#define QT 256
#define NTILE (NPTS / QT)    // 8
#define NSEG 8               // waves per block
#define RB 4                 // rows per lane
#define ROWS 8               // rows per block (2 half-waves x RB)
#define LOG2E 1.4426950408889634f

#if defined(__has_builtin)
#if __has_builtin(__builtin_amdgcn_exp2f)
#define EXP2F(x) __builtin_amdgcn_exp2f(x)
#endif
#endif
#ifndef EXP2F
#define EXP2F(x) exp2f(x)
#endif

__device__ __forceinline__ float gelu_tanh(float x) {
    float x3 = x * x * x;
    float u = 0.7978845608028654f * (x + 0.044715f * x3);
    return 0.5f * x * (1.0f + tanhf(u));
}

// ---------------- lift: fq[n,c] = gelu(f_x[n]*W[c,0] + x[n]*W[c,1] + b[c]) ----------------
__global__ __launch_bounds__(256) void k_lift(const float* __restrict__ f_x,
                                              const float* __restrict__ x_grid,
                                              const float* __restrict__ W,
                                              const float* __restrict__ b,
                                              float* __restrict__ fq) {
    int t = blockIdx.x * 256 + threadIdx.x;
    if (t >= NPTS * CH) return;
    int n = t >> 5, c = t & 31;
    float v = f_x[n] * W[c * 2] + x_grid[n] * W[c * 2 + 1] + b[c];
    fq[t] = gelu_tanh(v);
}

// ---------------- one KNO layer ----------------
// 512 thr = 8 waves; wave = 2 half-waves (nr) x 32 channels; each lane owns RB=4 rows.
// Block covers ROWS=8 rows; grid 256 blocks (1/CU). Wave s consumes q-slice s*32..s*32+31
// of each 256-q tile. g = fq*w staged in LDS [q][CH] (linear, bank=c conflict-free reads).
// x read via scalar loads (readfirstlane-uniform index -> s_load, off the LDS pipe).
// arg = nb*(xn_r-xq)^2 = fma(xq, h + B_r, A_r), h = xq*nb shared across rows.
__global__ __launch_bounds__(512, 1) void k_layer(const float* __restrict__ fq_in,
                                                  float* __restrict__ fq_out,
                                                  const float* __restrict__ x_grid,
                                                  const float* __restrict__ qw,
                                                  const float* __restrict__ pw_W,
                                                  const float* __restrict__ pw_b,
                                                  const float* __restrict__ log_ell,
                                                  const float* __restrict__ log_sig,
                                                  int layer, int act) {
    __shared__ float gs[QT * CH];              // 32 KB tile of fq*w
    __shared__ float psum[NSEG * ROWS * CH];   // 8 KB partials

    const int tid = threadIdx.x;
    const int c = tid & 31;
    const int nr = (tid >> 5) & 1;
    const int sU = __builtin_amdgcn_readfirstlane(tid >> 6);   // wave id, uniform
    const int n0 = blockIdx.x * ROWS;

    const float ell2 = expf(2.0f * log_ell[layer * CH + c]);
    const float nb = -LOG2E / (2.0f * ell2);

    float A[RB], Bc[RB];
#pragma unroll
    for (int r = 0; r < RB; r++) {
        const float xn = x_grid[n0 + nr * RB + r];
        A[r] = nb * xn * xn;
        Bc[r] = -2.0f * nb * xn;
    }

    // staging: thread stages 16 floats as 4x float4 (consecutive), premultiplied by wq.
    // element e = j*2048 + tid*4 of the tile (linear [q][CH]); q = e>>5 uniform per float4.
    float4 st[4];
    float w4[4];
#pragma unroll
    for (int j = 0; j < 4; j++) {
        st[j] = *(const float4*)(fq_in + j * 2048 + tid * 4);
        w4[j] = qw[j * 64 + (tid >> 3)];
    }

    float acc0[RB] = {0.f, 0.f, 0.f, 0.f}, acc1[RB] = {0.f, 0.f, 0.f, 0.f};

    for (int t = 0; t < NTILE; t++) {
        __syncthreads();                        // previous tile fully consumed
#pragma unroll
        for (int j = 0; j < 4; j++) {
            const float w = w4[j];
            const float4 v = st[j];
            *(float4*)(gs + j * 2048 + tid * 4) =
                make_float4(v.x * w, v.y * w, v.z * w, v.w * w);
        }
        __syncthreads();                        // tile visible

        if (t + 1 < NTILE) {                    // prefetch next tile into regs (hides latency)
            const int base = (t + 1) * QT * CH + tid * 4;
#pragma unroll
            for (int j = 0; j < 4; j++) {
                st[j] = *(const float4*)(fq_in + base + j * 2048);
                w4[j] = qw[(t + 1) * QT + j * 64 + (tid >> 3)];
            }
        }

        const int qb = __builtin_amdgcn_readfirstlane(t * QT + sU * 32);
        const float* gp = gs + sU * 32 * CH + c;
#pragma unroll
        for (int k = 0; k < 32; k += 2) {
            const float xq0 = x_grid[qb + k];       // uniform -> s_load
            const float xq1 = x_grid[qb + k + 1];
            const float g0 = gp[k * CH];            // ds_read_b32, bank=c, conflict-free
            const float g1 = gp[(k + 1) * CH];
            const float h0 = xq0 * nb;
            const float h1 = xq1 * nb;
#pragma unroll
            for (int r = 0; r < RB; r++) {
                acc0[r] = fmaf(EXP2F(fmaf(xq0, h0 + Bc[r], A[r])), g0, acc0[r]);
                acc1[r] = fmaf(EXP2F(fmaf(xq1, h1 + Bc[r], A[r])), g1, acc1[r]);
            }
        }
    }

#pragma unroll
    for (int r = 0; r < RB; r++)
        psum[(sU * ROWS + nr * RB + r) * CH + c] = acc0[r] + acc1[r];
    __syncthreads();

    // epilogue: 256 threads finish the 8x32 outputs of this block
    if (tid < ROWS * CH) {
        const int cc = tid & 31, rr = tid >> 5;
        const int nn = n0 + rr;
        float sum = 0.0f;
#pragma unroll
        for (int ss = 0; ss < NSEG; ss++) sum += psum[(ss * ROWS + rr) * CH + cc];
        const float sig2 = expf(2.0f * log_sig[layer * CH + cc]);
        float skip = pw_b[layer * CH + cc];
        const float* Wrow = pw_W + (layer * CH + cc) * CH;
        const float* frow = fq_in + nn * CH;
#pragma unroll
        for (int k = 0; k < CH; k++) skip = fmaf(frow[k], Wrow[k], skip);
        float v = skip + sig2 * sum;
        if (act) v = gelu_tanh(v);
        fq_out[nn * CH + cc] = v;
    }
}

// ---------------- projection head ----------------
__global__ __launch_bounds__(256) void k_proj(const float* __restrict__ fq,
                                              const float* __restrict__ W1,
                                              const float* __restrict__ b1,
                                              const float* __restrict__ W2,
                                              const float* __restrict__ b2,
                                              const float* __restrict__ W3,
                                              const float* __restrict__ b3,
                                              float* __restrict__ out) {
    __shared__ float sW1[CH * CH], sW2[CH * CH], sb1[CH], sb2[CH], sW3[CH];
    const int tid = threadIdx.x;
    for (int i = tid; i < CH * CH; i += 256) { sW1[i] = W1[i]; sW2[i] = W2[i]; }
    if (tid < CH) { sb1[tid] = b1[tid]; sb2[tid] = b2[tid]; sW3[tid] = W3[tid]; }
    __syncthreads();

    const int n = blockIdx.x * 256 + tid;
    float h0[CH], h1[CH];
    const float* row = fq + n * CH;
#pragma unroll
    for (int k = 0; k < CH; k++) h0[k] = row[k];

#pragma unroll
    for (int j = 0; j < CH; j++) {
        float ss = sb1[j];
#pragma unroll
        for (int k = 0; k < CH; k++) ss = fmaf(h0[k], sW1[j * CH + k], ss);
        h1[j] = gelu_tanh(ss);
    }
#pragma unroll
    for (int j = 0; j < CH; j++) {
        float ss = sb2[j];
#pragma unroll
        for (int k = 0; k < CH; k++) ss = fmaf(h1[k], sW2[j * CH + k], ss);
        h0[j] = gelu_tanh(ss);
    }
    float ss = b3[0];
#pragma unroll
    for (int k = 0; k < CH; k++) ss = fmaf(h0[k], sW3[k], ss);
    out[n] = ss;
}

extern "C" void kernel_launch(void* const* d_in, const int* in_sizes, int n_in,
                              void* d_out, int out_size, void* d_ws, size_t ws_size,
                              hipStream_t stream) {
    const float* f_x     = (const float*)d_in[0];
    const float* x_grid  = (const float*)d_in[1];
    const float* qw      = (const float*)d_in[2];
    const float* lift_W  = (const float*)d_in[3];
    const float* lift_b  = (const float*)d_in[4];
    const float* pw_W    = (const float*)d_in[5];
    const float* pw_b    = (const float*)d_in[6];
    const float* kle     = (const float*)d_in[7];
    const float* kls     = (const float*)d_in[8];
    const float* p1W     = (const float*)d_in[9];
    const float* p1b     = (const float*)d_in[10];
    const float* p2W     = (const float*)d_in[11];
    const float* p2b     = (const float*)d_in[12];
    const float* p3W     = (const float*)d_in[13];
    const float* p3b     = (const float*)d_in[14];

    float* fqA = (float*)d_ws;
    float* fqB = fqA + NPTS * CH;

    k_lift<<<NPTS * CH / 256, 256, 0, stream>>>(f_x, x_grid, lift_W, lift_b, fqA);
    k_layer<<<NPTS / ROWS, 512, 0, stream>>>(fqA, fqB, x_grid, qw, pw_W, pw_b, kle, kls, 0, 1);
    k_layer<<<NPTS / ROWS, 512, 0, stream>>>(fqB, fqA, x_grid, qw, pw_W, pw_b, kle, kls, 1, 1);
    k_layer<<<NPTS / ROWS, 512, 0, stream>>>(fqA, fqB, x_grid, qw, pw_W, pw_b, kle, kls, 2, 0);
    k_proj<<<NPTS / 256, 256, 0, stream>>>(fqB, p1W, p1b, p2W, p2b, p3W, p3b,
                                           (float*)d_out);
}

// Round 6
// 69.795 us; speedup vs baseline: 1.5010x; 1.5010x over previous
//
#include <hip/hip_runtime.h>
#include <hip/hip_bf16.h>

#define NPTS 2048
#define CH 32
#define KT 40                 // Taylor terms
#define LOG2E 1.4426950408889634f

#if defined(__has_builtin)
#if __has_builtin(__builtin_amdgcn_exp2f)
#define EXP2F(x) __builtin_amdgcn_exp2f(x)
#endif
#endif
#ifndef EXP2F
#define EXP2F(x) exp2f(x)
#endif

__device__ __forceinline__ float gelu_tanh(float x) {
    float x3 = x * x * x;
    float u = 0.7978845608028654f * (x + 0.044715f * x3);
    return 0.5f * x * (1.0f + tanhf(u));
}

// ---------------- lift: fq[n,c] = gelu(f_x[n]*W[c,0] + x[n]*W[c,1] + b[c]) ----------------
__global__ __launch_bounds__(256) void k_lift(const float* __restrict__ f_x,
                                              const float* __restrict__ x_grid,
                                              const float* __restrict__ W,
                                              const float* __restrict__ b,
                                              float* __restrict__ fq) {
    int t = blockIdx.x * 256 + threadIdx.x;
    if (t >= NPTS * CH) return;
    int n = t >> 5, c = t & 31;
    float v = f_x[n] * W[c * 2] + x_grid[n] * W[c * 2 + 1] + b[c];
    fq[t] = gelu_tanh(v);
}

// ---------------- moments: M[k,c] = sum_q e^{-xq^2 invl2_c/2} (xq invl2_c)^k / k! * fq[q,c] w[q] ----
// grid: 32 blocks (one channel each) x 256 threads; thread covers q = tid, tid+256, ... (8 q's).
__global__ __launch_bounds__(256) void k_mom(const float* __restrict__ fq,
                                             const float* __restrict__ x_grid,
                                             const float* __restrict__ qw,
                                             const float* __restrict__ log_ell,
                                             int layer,
                                             float* __restrict__ M) {
    __shared__ float wred[4 * KT];
    const int c = blockIdx.x;
    const int tid = threadIdx.x;

    const float invl2 = expf(-2.0f * log_ell[layer * CH + c]);   // 1/ell^2
    const float nb2 = -0.5f * invl2 * LOG2E;                     // exp2(x^2*nb2) = e^{-x^2 invl2/2}

    float m[KT];
#pragma unroll
    for (int k = 0; k < KT; k++) m[k] = 0.0f;

    for (int q = tid; q < NPTS; q += 256) {
        const float xq = x_grid[q];
        float h = EXP2F(xq * xq * nb2) * fq[q * CH + c] * qw[q];
        const float t = xq * invl2;
        m[0] += h;
#pragma unroll
        for (int k = 1; k < KT; k++) {
            h *= t * (1.0f / (float)k);
            m[k] += h;
        }
    }

    // reduce across 256 threads: wave shuffle then 4-wave LDS combine
#pragma unroll
    for (int k = 0; k < KT; k++) {
        float v = m[k];
        for (int off = 32; off; off >>= 1) v += __shfl_down(v, off);
        if ((tid & 63) == 0) wred[(tid >> 6) * KT + k] = v;
    }
    __syncthreads();
    if (tid < KT) {
        float s = wred[tid] + wred[KT + tid] + wred[2 * KT + tid] + wred[3 * KT + tid];
        M[tid * CH + c] = s;    // layout [k][c]
    }
}

// ---------------- apply: fq_out[n,c] = act( skip + sig2*e^{-xn^2 invl2/2} * Horner_k(xn; M[:,c]) ) ----
// grid: 256 blocks x 256 threads; thread = (row r = tid>>5 of 8, channel c = tid&31)
__global__ __launch_bounds__(256) void k_app(const float* __restrict__ fq_in,
                                             const float* __restrict__ M,
                                             const float* __restrict__ x_grid,
                                             const float* __restrict__ pw_W,
                                             const float* __restrict__ pw_b,
                                             const float* __restrict__ log_ell,
                                             const float* __restrict__ log_sig,
                                             int layer, int act,
                                             float* __restrict__ fq_out) {
    __shared__ float sM[KT * CH];      // [k][c]
    __shared__ float sWt[CH * CH];     // [k][c] = pw_W[c][k] transposed
    __shared__ float srow[8 * CH];

    const int tid = threadIdx.x;
    for (int i = tid; i < KT * CH; i += 256) sM[i] = M[i];
    for (int i = tid; i < CH * CH; i += 256) {
        const int k = i >> 5, c = i & 31;
        sWt[i] = pw_W[layer * CH * CH + c * CH + k];
    }
    const int r = tid >> 5, c = tid & 31;
    const int n = blockIdx.x * 8 + r;
    srow[tid] = fq_in[n * CH + c];
    __syncthreads();

    const float invl2 = expf(-2.0f * log_ell[layer * CH + c]);
    const float sig2 = expf(2.0f * log_sig[layer * CH + c]);
    const float xn = x_grid[n];

    float mreg[KT];
#pragma unroll
    for (int k = 0; k < KT; k++) mreg[k] = sM[k * CH + c];

    float P = mreg[KT - 1];
#pragma unroll
    for (int k = KT - 2; k >= 0; k--) P = fmaf(P, xn, mreg[k]);

    const float pref = EXP2F(xn * xn * (-0.5f * invl2 * LOG2E));
    const float integ = sig2 * pref * P;

    float skip = pw_b[layer * CH + c];
#pragma unroll
    for (int k = 0; k < CH; k++) skip = fmaf(srow[r * CH + k], sWt[k * CH + c], skip);

    float v = skip + integ;
    if (act) v = gelu_tanh(v);
    fq_out[n * CH + c] = v;
}

// ---------------- final layer apply (no act) + projection head fused ----------------
__global__ __launch_bounds__(256) void k_app2(const float* __restrict__ fq_in,
                                              const float* __restrict__ M,
                                              const float* __restrict__ x_grid,
                                              const float* __restrict__ pw_W,
                                              const float* __restrict__ pw_b,
                                              const float* __restrict__ log_ell,
                                              const float* __restrict__ log_sig,
                                              int layer,
                                              const float* __restrict__ W1,
                                              const float* __restrict__ b1,
                                              const float* __restrict__ W2,
                                              const float* __restrict__ b2,
                                              const float* __restrict__ W3,
                                              const float* __restrict__ b3,
                                              float* __restrict__ out) {
    __shared__ float sM[KT * CH];
    __shared__ float sWt[CH * CH];
    __shared__ float sW1t[CH * CH], sW2t[CH * CH];
    __shared__ float sb1[CH], sb2[CH], sW3[CH];
    __shared__ float srow[8 * CH];
    __shared__ float sh1[8 * CH], sh2[8 * CH];

    const int tid = threadIdx.x;
    for (int i = tid; i < KT * CH; i += 256) sM[i] = M[i];
    for (int i = tid; i < CH * CH; i += 256) {
        const int k = i >> 5, c = i & 31;
        sWt[i] = pw_W[layer * CH * CH + c * CH + k];
        sW1t[i] = W1[c * CH + k];
        sW2t[i] = W2[c * CH + k];
    }
    if (tid < CH) { sb1[tid] = b1[tid]; sb2[tid] = b2[tid]; sW3[tid] = W3[tid]; }
    const int r = tid >> 5, c = tid & 31;
    const int n = blockIdx.x * 8 + r;
    srow[tid] = fq_in[n * CH + c];
    __syncthreads();

    const float invl2 = expf(-2.0f * log_ell[layer * CH + c]);
    const float sig2 = expf(2.0f * log_sig[layer * CH + c]);
    const float xn = x_grid[n];

    float mreg[KT];
#pragma unroll
    for (int k = 0; k < KT; k++) mreg[k] = sM[k * CH + c];
    float P = mreg[KT - 1];
#pragma unroll
    for (int k = KT - 2; k >= 0; k--) P = fmaf(P, xn, mreg[k]);
    const float pref = EXP2F(xn * xn * (-0.5f * invl2 * LOG2E));
    const float integ = sig2 * pref * P;

    float skip = pw_b[layer * CH + c];
#pragma unroll
    for (int k = 0; k < CH; k++) skip = fmaf(srow[r * CH + k], sWt[k * CH + c], skip);

    __syncthreads();                 // reuse srow as fq2 row buffer
    srow[tid] = skip + integ;        // final layer: no activation
    __syncthreads();

    // proj1: h1[r][j] = gelu(b1[j] + sum_k fq2[r][k] W1[j][k])
    {
        float s = sb1[c];
#pragma unroll
        for (int k = 0; k < CH; k++) s = fmaf(srow[r * CH + k], sW1t[k * CH + c], s);
        sh1[tid] = gelu_tanh(s);
    }
    __syncthreads();
    {
        float s = sb2[c];
#pragma unroll
        for (int k = 0; k < CH; k++) s = fmaf(sh1[r * CH + k], sW2t[k * CH + c], s);
        sh2[tid] = gelu_tanh(s);
    }
    __syncthreads();
    if (tid < 8) {
        float s = b3[0];
#pragma unroll
        for (int k = 0; k < CH; k++) s = fmaf(sh2[tid * CH + k], sW3[k], s);
        out[blockIdx.x * 8 + tid] = s;
    }
}

extern "C" void kernel_launch(void* const* d_in, const int* in_sizes, int n_in,
                              void* d_out, int out_size, void* d_ws, size_t ws_size,
                              hipStream_t stream) {
    const float* f_x     = (const float*)d_in[0];
    const float* x_grid  = (const float*)d_in[1];
    const float* qw      = (const float*)d_in[2];
    const float* lift_W  = (const float*)d_in[3];
    const float* lift_b  = (const float*)d_in[4];
    const float* pw_W    = (const float*)d_in[5];
    const float* pw_b    = (const float*)d_in[6];
    const float* kle     = (const float*)d_in[7];
    const float* kls     = (const float*)d_in[8];
    const float* p1W     = (const float*)d_in[9];
    const float* p1b     = (const float*)d_in[10];
    const float* p2W     = (const float*)d_in[11];
    const float* p2b     = (const float*)d_in[12];
    const float* p3W     = (const float*)d_in[13];
    const float* p3b     = (const float*)d_in[14];

    float* fqA = (float*)d_ws;
    float* fqB = fqA + NPTS * CH;
    float* M   = fqB + NPTS * CH;

    k_lift<<<NPTS * CH / 256, 256, 0, stream>>>(f_x, x_grid, lift_W, lift_b, fqA);

    k_mom<<<CH, 256, 0, stream>>>(fqA, x_grid, qw, kle, 0, M);
    k_app<<<NPTS / 8, 256, 0, stream>>>(fqA, M, x_grid, pw_W, pw_b, kle, kls, 0, 1, fqB);

    k_mom<<<CH, 256, 0, stream>>>(fqB, x_grid, qw, kle, 1, M);
    k_app<<<NPTS / 8, 256, 0, stream>>>(fqB, M, x_grid, pw_W, pw_b, kle, kls, 1, 1, fqA);

    k_mom<<<CH, 256, 0, stream>>>(fqA, x_grid, qw, kle, 2, M);
    k_app2<<<NPTS / 8, 256, 0, stream>>>(fqA, M, x_grid, pw_W, pw_b, kle, kls, 2,
                                         p1W, p1b, p2W, p2b, p3W, p3b, (float*)d_out);
}